// Round 1
// baseline (2724.192 us; speedup 1.0000x reference)
//
#include <hip/hip_runtime.h>

// GraphWaveNet block: gated inception conv -> 2x mixprop (fwd/rev) + residual, skip = h@Ws+bs
// B=8 T=256 N=512 C=64. All heavy GEMMs in bf16 MFMA 16x16x32, fp32 accum.

typedef short     s16x8 __attribute__((ext_vector_type(8)));
typedef unsigned short u16x4 __attribute__((ext_vector_type(4)));
typedef float     f32x4 __attribute__((ext_vector_type(4)));
typedef float     f32x4v __attribute__((ext_vector_type(4)));

__device__ __forceinline__ unsigned short f2bf(float f){
  union { float f; unsigned u; } v; v.f = f;
  unsigned r = v.u + 0x7FFFu + ((v.u >> 16) & 1u);   // RNE
  return (unsigned short)(r >> 16);
}

__device__ __forceinline__ f32x4 mfma16(s16x8 a, s16x8 b, f32x4 c){
  return __builtin_amdgcn_mfma_f32_16x16x32_bf16(a, b, c, 0, 0, 0);
}

// ---------------- preprocess: row-normalized adjacency (fwd + rev), bf16 ----------------
__global__ void k_adj(const float* __restrict__ adj,
                      unsigned short* __restrict__ Af,
                      unsigned short* __restrict__ Ar){
  __shared__ float red[256];
  int n = blockIdx.x, tid = threadIdx.x;
  float rv0 = adj[n*512 + tid], rv1 = adj[n*512 + tid + 256];
  red[tid] = rv0 + rv1; __syncthreads();
  for (int o = 128; o > 0; o >>= 1){ if (tid < o) red[tid] += red[tid+o]; __syncthreads(); }
  float rs = red[0] + 1.0f;           // + self loop
  __syncthreads();
  float cv0 = adj[tid*512 + n], cv1 = adj[(tid+256)*512 + n];
  red[tid] = cv0 + cv1; __syncthreads();
  for (int o = 128; o > 0; o >>= 1){ if (tid < o) red[tid] += red[tid+o]; __syncthreads(); }
  float cs = red[0] + 1.0f;
  float ir = 1.0f / fmaxf(rs, 1e-9f), ic = 1.0f / fmaxf(cs, 1e-9f);
  Af[n*512 + tid]       = f2bf((rv0 + (tid==n ? 1.f:0.f)) * ir);
  Af[n*512 + tid + 256] = f2bf((rv1 + (tid+256==n ? 1.f:0.f)) * ir);
  Ar[n*512 + tid]       = f2bf((cv0 + (tid==n ? 1.f:0.f)) * ic);
  Ar[n*512 + tid + 256] = f2bf((cv1 + (tid+256==n ? 1.f:0.f)) * ic);
}

// ------------- preprocess: concat conv weights into B^T layout [cout][d*64+cin] bf16 -------------
__global__ void k_wcat(const float* __restrict__ wf0, const float* __restrict__ wf1,
                       const float* __restrict__ wf2, const float* __restrict__ wf3,
                       const float* __restrict__ wg0, const float* __restrict__ wg1,
                       const float* __restrict__ wg2, const float* __restrict__ wg3,
                       unsigned short* __restrict__ WF, unsigned short* __restrict__ WG){
  int id = blockIdx.x * 256 + threadIdx.x;
  if (id >= 64*448) return;
  int cout = id / 448, k = id % 448;
  int d = k >> 6, cin = k & 63;
  int br = cout >> 4, j = cout & 15;
  int kb = (br==0)?2:(br==1)?3:(br==2)?6:7;
  float vf = 0.f, vg = 0.f;
  if (d < kb){
    int tau = kb - 1 - d;  // y[t] = sum_tau w[tau] x[t-(k-1)+tau]  => tap depth d uses w[k-1-d]
    const float* wf = (br==0)?wf0:(br==1)?wf1:(br==2)?wf2:wf3;
    const float* wg = (br==0)?wg0:(br==1)?wg1:(br==2)?wg2:wg3;
    vf = wf[(tau*64 + cin)*16 + j];
    vg = wg[(tau*64 + cin)*16 + j];
  }
  WF[id] = f2bf(vf);
  WG[id] = f2bf(vg);
}

// ------------- preprocess: folded projection weights, B^T layout [cout][cin] bf16 -------------
// out = H*Wt0 + P1f*Wt1f + P2f*Wt2f + P1r*Wt1r + P2r*Wt2r + x + (bgf+bgr)
__global__ void k_wtil(const float* __restrict__ Wgf, const float* __restrict__ Wgr,
                       const float* __restrict__ Ws,
                       unsigned short* __restrict__ W0, unsigned short* __restrict__ W1f,
                       unsigned short* __restrict__ W2f, unsigned short* __restrict__ W1r,
                       unsigned short* __restrict__ W2r, unsigned short* __restrict__ WsT){
  int id = blockIdx.x*256 + threadIdx.x;
  if (id >= 4096) return;
  int cout = id >> 6, cin = id & 63;
  const float a = 0.05f, b = 0.95f;
  float f0 = Wgf[cin*64+cout], f1 = Wgf[(64+cin)*64+cout], f2 = Wgf[(128+cin)*64+cout];
  float r0 = Wgr[cin*64+cout], r1 = Wgr[(64+cin)*64+cout], r2 = Wgr[(128+cin)*64+cout];
  int o = cout*64 + cin;
  W0[o]  = f2bf(f0 + a*(f1+f2) + r0 + a*(r1+r2));
  W1f[o] = f2bf(b*f1 + a*b*f2);
  W2f[o] = f2bf(b*b*f2);
  W1r[o] = f2bf(b*r1 + a*b*r2);
  W2r[o] = f2bf(b*b*r2);
  WsT[o] = f2bf(Ws[cin*64+cout]);
}

// ---------------- gated inception conv: h = tanh(f)*sigmoid(g), bf16, written as [b,t,c,n] ----------------
// grid (8 tsplit, 8 nodechunk, 8 b), 256 threads (4 waves = 4 branches)
__global__ __launch_bounds__(256, 4)
void k_conv(const float* __restrict__ x,
            const unsigned short* __restrict__ WF, const unsigned short* __restrict__ WG,
            const float* __restrict__ bf0, const float* __restrict__ bf1,
            const float* __restrict__ bf2, const float* __restrict__ bf3,
            const float* __restrict__ bg0, const float* __restrict__ bg1,
            const float* __restrict__ bg2, const float* __restrict__ bg3,
            unsigned short* __restrict__ hT){
  __shared__ __align__(16) unsigned short Xw[7*64*64];  // 7-slice rolling window, ch-block swizzled
  int tid = threadIdx.x;
  int t0 = blockIdx.x * 32, n0 = blockIdx.y * 64, b = blockIdx.z;
  int w = tid >> 6, lane = tid & 63, q = lane >> 4, lr = lane & 15;
  int kw = (w==0)?2:(w==1)?3:(w==2)?6:7;
  const float* bfp = (w==0)?bf0:(w==1)?bf1:(w==2)?bf2:bf3;
  const float* bgp = (w==0)?bg0:(w==1)?bg1:(w==2)?bg2:bg3;
  float bfv = bfp[lr], bgv = bgp[lr];
  int cout = w*16 + lr;

  auto stage = [&](int tau){
    int slot = (tau + 7) % 7;   // tau >= -6
    #pragma unroll
    for (int i = 0; i < 4; ++i){
      int fidx = i*256 + tid;            // float4 index in [64n x 16]
      int n = fidx >> 4, c = (fidx & 15) * 4;
      f32x4v v = {0.f, 0.f, 0.f, 0.f};
      if (tau >= 0){
        v = *(const f32x4v*)&x[(((b*256 + tau)*512) + n0 + n)*64 + c];
      }
      u16x4 p; p[0]=f2bf(v[0]); p[1]=f2bf(v[1]); p[2]=f2bf(v[2]); p[3]=f2bf(v[3]);
      int addr = slot*4096 + n*64 + ((((c>>3) ^ (n&7)) & 7) << 3) + (c & 7);
      *(u16x4*)&Xw[addr] = p;
    }
  };
  for (int tau = t0-6; tau <= t0; ++tau) stage(tau);
  __syncthreads();

  for (int tl = 0; tl < 32; ++tl){
    int t = t0 + tl;
    f32x4 accf[4], accg[4];
    #pragma unroll
    for (int mi = 0; mi < 4; ++mi){ accf[mi] = (f32x4){0,0,0,0}; accg[mi] = (f32x4){0,0,0,0}; }
    for (int d = 0; d < kw; ++d){
      int slot = (t - d + 7) % 7;
      #pragma unroll
      for (int kk = 0; kk < 2; ++kk){
        int kbase = d*64 + kk*32 + q*8;
        s16x8 bfr = *(const s16x8*)&WF[cout*448 + kbase];
        s16x8 bgr_ = *(const s16x8*)&WG[cout*448 + kbase];
        #pragma unroll
        for (int mi = 0; mi < 4; ++mi){
          int n = mi*16 + lr;
          int cb = kk*4 + q;
          s16x8 a = *(const s16x8*)&Xw[slot*4096 + n*64 + (((cb ^ (n&7)) & 7) << 3)];
          accf[mi] = mfma16(a, bfr, accf[mi]);
          accg[mi] = mfma16(a, bgr_, accg[mi]);
        }
      }
    }
    // gate + transposed bf16 store to h region [b,t,c,n]
    unsigned short* hs = hT + (size_t)(b*256 + t) * 65536;
    #pragma unroll
    for (int mi = 0; mi < 4; ++mi){
      u16x4 pv;
      #pragma unroll
      for (int r = 0; r < 4; ++r){
        float f = accf[mi][r] + bfv;
        float g = accg[mi][r] + bgv;
        float th = 2.f / (1.f + __expf(-2.f*f)) - 1.f;
        float sg = 1.f / (1.f + __expf(-g));
        pv[r] = f2bf(th * sg);
      }
      *(u16x4*)&hs[cout*512 + (n0 + mi*16 + q*4)] = pv;
    }
    __syncthreads();
    if (tl < 31){ stage(t+1); __syncthreads(); }
  }
}

// ---------------- mixprop fwd+rev + projections + skip + residual ----------------
// grid (256 t, 8 b), 512 threads (8 waves; wave w owns output nodes 64w..64w+63)
__global__ __launch_bounds__(512, 2)
void k_mix(const float* __restrict__ x,
           const unsigned short* __restrict__ hT,
           const unsigned short* __restrict__ Af, const unsigned short* __restrict__ Ar,
           const unsigned short* __restrict__ W0, const unsigned short* __restrict__ W1f,
           const unsigned short* __restrict__ W2f, const unsigned short* __restrict__ W1r,
           const unsigned short* __restrict__ W2r, const unsigned short* __restrict__ WsT,
           const float* __restrict__ bgf, const float* __restrict__ bgr,
           const float* __restrict__ bs,
           float* __restrict__ outp, float* __restrict__ skipp){
  __shared__ __align__(16) unsigned short Hb[64*512];  // exactly 64KB, [ch][node] with swizzled node blocks
  int tid = threadIdx.x;
  int t = blockIdx.x, b = blockIdx.y;
  int w = tid >> 6, lane = tid & 63, q = lane >> 4, lr = lane & 15;
  const unsigned short* hs = hT + (size_t)(b*256 + t) * 65536;

  f32x4 oacc[4][4];
  #pragma unroll
  for (int i=0;i<4;i++){
    #pragma unroll
    for (int j=0;j<4;j++) oacc[i][j] = (f32x4){0,0,0,0};
  }
  f32x4 pacc[4][4];

  // swizzled address: node blocks (bits 3-5) XORed by ch&7, rotated by ch>>3 -> conflict-free b128 + ~2-way u16
  auto haddr = [&](int c, int n){
    int sw = ((((n>>3)&7) ^ (c&7)) + (c>>3)) & 7;
    return c*512 + (n & 448) + sw*8 + (n & 7);
  };

  auto stageH = [&](){
    #pragma unroll
    for (int i = 0; i < 8; ++i){
      int fidx = i*512 + tid;
      int c = fidx >> 6, jb = fidx & 63;
      s16x8 v = *(const s16x8*)&hs[c*512 + jb*8];
      int sw = (((jb & 7) ^ (c & 7)) + (c >> 3)) & 7;
      *(s16x8*)&Hb[c*512 + (jb & 56)*8 + sw*8] = v;
    }
  };

  auto pgemm = [&](const unsigned short* __restrict__ A){
    #pragma unroll
    for (int i=0;i<4;i++){
      #pragma unroll
      for (int j=0;j<4;j++) pacc[i][j] = (f32x4){0,0,0,0};
    }
    for (int k = 0; k < 16; ++k){
      s16x8 bfr[4];
      #pragma unroll
      for (int ni = 0; ni < 4; ++ni){
        int c = ni*16 + lr;
        int nb = k*4 + q;
        int sw = (((nb & 7) ^ (c & 7)) + (c >> 3)) & 7;
        bfr[ni] = *(const s16x8*)&Hb[c*512 + (nb & 56)*8 + sw*8];
      }
      #pragma unroll
      for (int mi = 0; mi < 4; ++mi){
        s16x8 a = *(const s16x8*)&A[(size_t)(w*64 + mi*16 + lr)*512 + k*32 + q*8];
        #pragma unroll
        for (int ni = 0; ni < 4; ++ni)
          pacc[mi][ni] = mfma16(a, bfr[ni], pacc[mi][ni]);
      }
    }
  };

  auto writeP = [&](){
    #pragma unroll
    for (int mi = 0; mi < 4; ++mi){
      int nb_ = w*64 + mi*16 + q*4;
      #pragma unroll
      for (int ni = 0; ni < 4; ++ni){
        int c = ni*16 + lr;
        u16x4 v;
        v[0]=f2bf(pacc[mi][ni][0]); v[1]=f2bf(pacc[mi][ni][1]);
        v[2]=f2bf(pacc[mi][ni][2]); v[3]=f2bf(pacc[mi][ni][3]);
        *(u16x4*)&Hb[haddr(c, nb_)] = v;
      }
    }
  };

  auto proj = [&](const unsigned short* __restrict__ Wt, f32x4 (*acc)[4]){
    #pragma unroll
    for (int k2 = 0; k2 < 2; ++k2){
      s16x8 af[4];
      #pragma unroll
      for (int mi = 0; mi < 4; ++mi){
        int n = w*64 + mi*16 + lr;
        s16x8 tv;
        #pragma unroll
        for (int j = 0; j < 8; ++j){
          int c = k2*32 + q*8 + j;
          tv[j] = (short)Hb[haddr(c, n)];
        }
        af[mi] = tv;
      }
      #pragma unroll
      for (int ni = 0; ni < 4; ++ni){
        s16x8 bw = *(const s16x8*)&Wt[(ni*16 + lr)*64 + k2*32 + q*8];
        #pragma unroll
        for (int mi = 0; mi < 4; ++mi)
          acc[mi][ni] = mfma16(af[mi], bw, acc[mi][ni]);
      }
    }
  };

  // ---- forward diffusion ----
  stageH(); __syncthreads();
  proj(W0, oacc);                       // H * Wt0 (fwd+rev H-terms folded)
  pgemm(Af); __syncthreads(); writeP(); __syncthreads();   // Hb <- P1f
  proj(W1f, oacc);
  pgemm(Af); __syncthreads(); writeP(); __syncthreads();   // Hb <- P2f
  proj(W2f, oacc);
  __syncthreads();
  // ---- re-stage H for skip + reverse ----
  stageH(); __syncthreads();
  {
    f32x4 sacc[4][4];
    #pragma unroll
    for (int i=0;i<4;i++){
      #pragma unroll
      for (int j=0;j<4;j++) sacc[i][j] = (f32x4){0,0,0,0};
    }
    proj(WsT, sacc);                    // skip = H @ Ws + bs
    float* sp = skipp + (size_t)(b*256 + t) * 32768;  // overwrites h slice: all h reads done
    #pragma unroll
    for (int ni = 0; ni < 4; ++ni){
      float bsv = bs[ni*16 + lr];
      #pragma unroll
      for (int mi = 0; mi < 4; ++mi){
        #pragma unroll
        for (int r = 0; r < 4; ++r)
          sp[(w*64 + mi*16 + q*4 + r)*64 + ni*16 + lr] = sacc[mi][ni][r] + bsv;
      }
    }
  }
  pgemm(Ar); __syncthreads(); writeP(); __syncthreads();   // Hb <- P1r
  proj(W1r, oacc);
  pgemm(Ar); __syncthreads(); writeP(); __syncthreads();   // Hb <- P2r
  proj(W2r, oacc);

  // ---- epilogue: + x + (bgf+bgr) ----
  const float* xs = x + (size_t)(b*256 + t) * 32768;
  float* op = outp + (size_t)(b*256 + t) * 32768;
  #pragma unroll
  for (int ni = 0; ni < 4; ++ni){
    float bsv = bgf[ni*16 + lr] + bgr[ni*16 + lr];
    #pragma unroll
    for (int mi = 0; mi < 4; ++mi){
      #pragma unroll
      for (int r = 0; r < 4; ++r){
        int idx = (w*64 + mi*16 + q*4 + r)*64 + ni*16 + lr;
        op[idx] = oacc[mi][ni][r] + xs[idx] + bsv;
      }
    }
  }
}

extern "C" void kernel_launch(void* const* d_in, const int* in_sizes, int n_in,
                              void* d_out, int out_size, void* d_ws, size_t ws_size,
                              hipStream_t stream){
  const float* x   = (const float*)d_in[0];
  const float* adj = (const float*)d_in[1];
  const float* wf0 = (const float*)d_in[2];
  const float* bf0 = (const float*)d_in[3];
  const float* wg0 = (const float*)d_in[4];
  const float* bg0 = (const float*)d_in[5];
  const float* wf1 = (const float*)d_in[6];
  const float* bf1 = (const float*)d_in[7];
  const float* wg1 = (const float*)d_in[8];
  const float* bg1 = (const float*)d_in[9];
  const float* wf2 = (const float*)d_in[10];
  const float* bf2 = (const float*)d_in[11];
  const float* wg2 = (const float*)d_in[12];
  const float* bg2 = (const float*)d_in[13];
  const float* wf3 = (const float*)d_in[14];
  const float* bf3 = (const float*)d_in[15];
  const float* wg3 = (const float*)d_in[16];
  const float* bg3 = (const float*)d_in[17];
  const float* Wgf = (const float*)d_in[18];
  const float* bgf = (const float*)d_in[19];
  const float* Wgr = (const float*)d_in[20];
  const float* bgr = (const float*)d_in[21];
  const float* Ws  = (const float*)d_in[22];
  const float* bs  = (const float*)d_in[23];

  float* outp  = (float*)d_out;
  float* skipp = outp + (size_t)67108864;          // second output region
  unsigned short* hT = (unsigned short*)skipp;     // h staged (bf16, [b,t,c,n]) in skip region

  unsigned short* Af  = (unsigned short*)d_ws;     // ws layout (~1.2 MB total)
  unsigned short* Ar  = Af  + 512*512;
  unsigned short* WF  = Ar  + 512*512;
  unsigned short* WG  = WF  + 64*448;
  unsigned short* W0  = WG  + 64*448;
  unsigned short* W1f = W0  + 4096;
  unsigned short* W2f = W1f + 4096;
  unsigned short* W1r = W2f + 4096;
  unsigned short* W2r = W1r + 4096;
  unsigned short* WsT = W2r + 4096;

  k_adj <<<512, 256, 0, stream>>>(adj, Af, Ar);
  k_wcat<<<112, 256, 0, stream>>>(wf0,wf1,wf2,wf3, wg0,wg1,wg2,wg3, WF, WG);
  k_wtil<<<16,  256, 0, stream>>>(Wgf, Wgr, Ws, W0, W1f, W2f, W1r, W2r, WsT);
  k_conv<<<dim3(8,8,8), 256, 0, stream>>>(x, WF, WG, bf0,bf1,bf2,bf3, bg0,bg1,bg2,bg3, hT);
  k_mix <<<dim3(256,8), 512, 0, stream>>>(x, hT, Af, Ar, W0,W1f,W2f,W1r,W2r,WsT,
                                          bgf, bgr, bs, outp, skipp);
}